// Round 1
// 818.112 us; speedup vs baseline: 1.0262x; 1.0262x over previous
//
#include <hip/hip_runtime.h>
#include <math.h>

#define N_NODES 50000
#define N_EDGES 800000

using bf16x8 = __attribute__((ext_vector_type(8))) short;
using f32x4  = __attribute__((ext_vector_type(4))) float;
typedef unsigned short u16;
typedef unsigned int   u32;

__device__ __forceinline__ u16 f2bf(float f) {
    union { float f; u32 u; } v; v.f = f;
    u32 u = v.u + 0x7fffu + ((v.u >> 16) & 1u);   // round-to-nearest-even
    return (u16)(u >> 16);
}
__device__ __forceinline__ float bf2f(u32 h) {
    union { u32 u; float f; } v; v.u = h << 16;
    return v.f;
}

#define SA_LD 136   // edge A tile leading dim (bf16), 16B-aligned rows
#define SW_LD 40    // weight-panel leading dim (mfma_gemm only)

// ---------------------------------------------------------------------------
// Generic bf16 MFMA GEMM: C[MxN](bf16) = act(A[MxK](bf16) @ W[NxK](bf16)^T + bias)
// 64x64 tile, 256 threads (4 waves, wave w owns m-subtile w), K-step 32.
// ---------------------------------------------------------------------------
template<bool RELU>
__global__ __launch_bounds__(256, 4)
void mfma_gemm(const u16* __restrict__ A, int lda,
               const u16* __restrict__ W, int ldw,
               const float* __restrict__ bias,
               u16* __restrict__ C, int ldc,
               int M, int N, int K)
{
    __shared__ u16 sA[64 * SW_LD];
    __shared__ u16 sW[64 * SW_LD];
    const int tid = threadIdx.x;
    const int w = tid >> 6, lane = tid & 63, lx = lane & 15, quad = lane >> 4;
    const int m0 = blockIdx.x * 64, n0 = blockIdx.y * 64;

    f32x4 acc[4];
#pragma unroll
    for (int nt = 0; nt < 4; ++nt) {
        float b = bias ? bias[n0 + nt * 16 + lx] : 0.f;
        f32x4 t; t[0] = b; t[1] = b; t[2] = b; t[3] = b; acc[nt] = t;
    }

    const int sr = tid >> 2;            // 0..63 panel row
    const int sseg = (tid & 3) * 8;     // k-offset within panel (4 thr/row x 8 elems = 32)
    const int ksteps = K >> 5;
    for (int ks = 0; ks < ksteps; ++ks) {
        const int k0 = ks * 32;
        __syncthreads();
        int am = m0 + sr; if (am >= M) am = M - 1;
        uint4 va = *(const uint4*)&A[(size_t)am * lda + k0 + sseg];
        *(uint4*)&sA[sr * SW_LD + sseg] = va;
        uint4 vw = *(const uint4*)&W[(size_t)(n0 + sr) * ldw + k0 + sseg];
        *(uint4*)&sW[sr * SW_LD + sseg] = vw;
        __syncthreads();
        bf16x8 af = *(const bf16x8*)&sA[(w * 16 + lx) * SW_LD + quad * 8];
#pragma unroll
        for (int nt = 0; nt < 4; ++nt) {
            bf16x8 bf = *(const bf16x8*)&sW[(nt * 16 + lx) * SW_LD + quad * 8];
            acc[nt] = __builtin_amdgcn_mfma_f32_16x16x32_bf16(af, bf, acc[nt], 0, 0, 0);
        }
    }
#pragma unroll
    for (int r = 0; r < 4; ++r) {
        int m = m0 + w * 16 + quad * 4 + r;
        if (m >= M) continue;
#pragma unroll
        for (int nt = 0; nt < 4; ++nt) {
            float v = acc[nt][r];
            if (RELU) v = fmaxf(v, 0.f);
            C[(size_t)m * ldc + n0 + nt * 16 + lx] = f2bf(v);
        }
    }
}

// ---------------------------------------------------------------------------
// Convert h_node fp32 -> bf16 (float4-wide)
// ---------------------------------------------------------------------------
__global__ void conv_hnode(const float* __restrict__ src, u16* __restrict__ dst)
{
    int idx = blockIdx.x * 256 + threadIdx.x;       // one float4 per thread
    if (idx >= N_NODES * 32) return;
    float4 v = ((const float4*)src)[idx];
    uint2 o;
    o.x = (u32)f2bf(v.x) | ((u32)f2bf(v.y) << 16);
    o.y = (u32)f2bf(v.z) | ((u32)f2bf(v.w) << 16);
    *(uint2*)&dst[(size_t)idx * 4] = o;
}

// ---------------------------------------------------------------------------
// Small weight conversions, flat-indexed.
// bond_bf / iw1_bf / gate_bf are emitted in MFMA FRAGMENT order:
//   flat t = (((g*4 + ks)*4 + quad)*16 + lx)*8 + e
//   n = g*16 + lx (output row), k = ks*32 + quad*8 + e
// so the edge kernel's wave (lane = quad*16+lx) reads 16B/lane CONTIGUOUS.
// ---------------------------------------------------------------------------
__global__ void prep_small(const float* lw1, const float* rw1,
                           const float* lb1, const float* rb1,
                           const float* bond_w, const float* iw1, const float* gw1,
                           const float* sw1,
                           u16* W1cat, float* b1cat, u16* bond_bf, u16* iw1_bf,
                           u16* gate_bf, u16* sw1c)
{
    int idx = blockIdx.x * 256 + threadIdx.x;
    if (idx < 32768) {
        int i = idx >> 7, k = idx & 127;
        float v = (i < 128) ? lw1[i * 128 + k] : rw1[(i - 128) * 128 + k];
        W1cat[idx] = f2bf(v);
    } else if (idx < 33024) {
        int i = idx - 32768;
        b1cat[i] = (i < 128) ? lb1[i] : rb1[i - 128];
    } else if (idx < 49408) {
        int t = idx - 33024;               // bond, frag order
        int e = t & 7, lx = (t >> 3) & 15, quad = (t >> 7) & 3;
        int ks = (t >> 9) & 3, g = t >> 11;
        int n = g * 16 + lx, k = ks * 32 + quad * 8 + e;
        bond_bf[t] = f2bf(bond_w[n * 128 + k]);
    } else if (idx < 65792) {
        int t = idx - 49408;               // inter_w1, frag order
        int e = t & 7, lx = (t >> 3) & 15, quad = (t >> 7) & 3;
        int ks = (t >> 9) & 3, g = t >> 11;
        int n = g * 16 + lx, k = ks * 32 + quad * 8 + e;
        iw1_bf[t] = f2bf(iw1[n * 128 + k]);
    } else if (idx < 69888) {
        int t = idx - 65792;               // gate (h_edge slice), frag order
        int e = t & 7, lx = (t >> 3) & 15, quad = (t >> 7) & 3;
        int ks = (t >> 9) & 3, g = t >> 11;
        int n = g * 16 + lx, k = ks * 32 + quad * 8 + e;
        gate_bf[t] = f2bf(gw1[(size_t)n * 386 + k]);
    } else if (idx < 90368) {
        int t = idx - 69888;
        int o = t / 160, k = t % 160;
        sw1c[t] = (k < 131) ? f2bf(sw1[(size_t)o * 131 + k]) : (u16)0;
    }
}

// ---------------------------------------------------------------------------
// Compose projection weights (fold lw2/rw2 into nodeb_lin_w & gate_w1 node slices)
// WP[320][256] bf16, rows PERMUTED for vectorized edge-kernel gathers:
//   rows   0..127 : Lp  block, orig col c = (r&7)*16 + (r>>3), K 0..127 (L half)
//   rows 128..159 : GLX block, orig col g = (r&1)*16 + (r>>1), K 0..127
//   rows 160..287 : Rp  block, K 128..255 (R half)
//   rows 288..319 : GR  block, K 128..255
// bP[320] float = composed bias at the same permuted positions.
// ---------------------------------------------------------------------------
__global__ void compose_wp(const float* __restrict__ nodeb_w, const float* __restrict__ gw1,
                           const float* __restrict__ lw2, const float* __restrict__ rw2,
                           const float* __restrict__ lb2, const float* __restrict__ rb2,
                           const float* __restrict__ gb1,
                           u16* __restrict__ WP, float* __restrict__ bP)
{
    int idx = blockIdx.x * 256 + threadIdx.x;
    if (idx >= 320 * 256) return;
    int i = idx >> 8;      // permuted output row 0..319
    int j = idx & 255;     // K index 0..255
    bool leftRow = (i < 160);
    bool leftK = (j < 128);
    if (leftRow != leftK) { WP[idx] = 0; return; }

    const float* src;      // 128-length fp32 row to compose
    const float* w2 = leftRow ? lw2 : rw2;
    const float* b2 = leftRow ? lb2 : rb2;
    float biasExtra = 0.f;
    if (i < 128) {
        int c = ((i & 7) << 4) + (i >> 3);
        src = nodeb_w + (size_t)c * 256;
    } else if (i < 160) {
        int r = i - 128, g = ((r & 1) << 4) + (r >> 1);
        src = gw1 + (size_t)g * 386 + 128;
        biasExtra = gb1[g];
    } else if (i < 288) {
        int r = i - 160, c = ((r & 7) << 4) + (r >> 3);
        src = nodeb_w + (size_t)c * 256 + 128;
    } else {
        int r = i - 288, g = ((r & 1) << 4) + (r >> 1);
        src = gw1 + (size_t)g * 386 + 256;
    }
    int jj = j & 127;
    float s = 0.f;
#pragma unroll 4
    for (int k = 0; k < 128; ++k)
        s += src[k] * w2[(size_t)k * 128 + jj];
    WP[idx] = f2bf(s);
    if (jj == 0) {
        float b = biasExtra;
        for (int k = 0; k < 128; ++k) b += src[k] * b2[k];
        bP[i] = b;
    }
}

// ---------------------------------------------------------------------------
// Add node_extra part into GLX block of P (bf16 RMW). gb1 already in bP.
// P layout per node: [Lp(128 perm) | GLX(32 perm) | Rp(128 perm) | GR(32 perm)]
// ---------------------------------------------------------------------------
__global__ void fix_glx(u16* __restrict__ P, const float* __restrict__ ne,
                        const float* __restrict__ gw1)
{
    int idx = blockIdx.x * 256 + threadIdx.x;
    if (idx >= N_NODES * 32) return;
    int n = idx >> 5, g = idx & 31;                       // g = original gate channel
    int pos = ((g & 15) << 1) + (g >> 4);                 // perm32
    u16* p = &P[(size_t)n * 320 + 128 + pos];
    float v = bf2f(*p) + ne[n * 2] * gw1[(size_t)g * 386 + 384]
                       + ne[n * 2 + 1] * gw1[(size_t)g * 386 + 385];
    *p = f2bf(v);
}

// ---------------------------------------------------------------------------
// Fused edge kernel (MFMA): 128 edges/block, 512 threads (8 waves x 16 edges).
// Weights in fragment order: staged ONCE per GEMM phase (linear copy), read
// conflict-free. 4 barriers/block total. P-gathers hoisted above GEMM1 so
// their L3 latency hides under the MFMAs.
// Per-wave sA rows are private: GEMM1 reads rows [16w,16w+16) only, the
// t-epilogue rewrites the same rows -> no barrier between GEMM1 and GEMM2
// except the sW restage pair.
// ---------------------------------------------------------------------------
__global__ __launch_bounds__(512, 4)
void edge_kernel(const float* __restrict__ he,
                 const int*   __restrict__ eidx,
                 const float* __restrict__ rel_vec,
                 const float* __restrict__ dist,
                 const u16*   __restrict__ P,
                 const u16*   __restrict__ bondw,
                 const u16*   __restrict__ iw1w,
                 const u16*   __restrict__ gatew,
                 const float* __restrict__ ib1,
                 const float* __restrict__ iw2,
                 const float* __restrict__ ib2,
                 const float* __restrict__ gw2,
                 const float* __restrict__ gb2,
                 float* __restrict__ dp)
{
    __shared__ u16 sA[128 * SA_LD];        // 34816 B
    __shared__ u16 sW[16384 + 4096];       // 40960 B: bond(32KB) + gate(8KB); iw1 restaged over bond
    __shared__ int sEL[128], sER[128];
    __shared__ float sG[128], sIS[128];

    const int tid = threadIdx.x;
    const int w = tid >> 6, lane = tid & 63, lx = lane & 15, quad = lane >> 4;
    const int eb = blockIdx.x * 128;

    if (tid < 128) { sEL[tid] = eidx[eb + tid]; sER[tid] = eidx[N_EDGES + eb + tid]; }

    // stage GEMM1 weights (fragment-order = linear copy, 16B/thread/iter)
#pragma unroll
    for (int j = 0; j < 4; ++j) {
        int t = j * 512 + tid;
        *(uint4*)&sW[t * 8] = *(const uint4*)&bondw[t * 8];
    }
    *(uint4*)&sW[16384 + tid * 8] = *(const uint4*)&gatew[tid * 8];

    // stage h_edge tile -> bf16 LDS (4096 float4 = 8 iters x 512 thr)
#pragma unroll
    for (int j = 0; j < 8; ++j) {
        int fid = j * 512 + tid;
        int e = fid >> 5, kq = (fid & 31) << 2;
        float4 v = *(const float4*)&he[(size_t)(eb + e) * 128 + kq];
        uint2 o;
        o.x = (u32)f2bf(v.x) | ((u32)f2bf(v.y) << 16);
        o.y = (u32)f2bf(v.z) | ((u32)f2bf(v.w) << 16);
        *(uint2*)&sA[e * SA_LD + kq] = o;
    }
    __syncthreads();                                        // B1: sA/sW/sEL ready

    // ---- early P gathers (hide L3 latency under GEMM1) ----
    uint4 lv[4], rv[4]; u32 gl[4], gr[4];
#pragma unroll
    for (int r = 0; r < 4; ++r) {
        int erow = w * 16 + quad * 4 + r;
        size_t lbase = (size_t)sEL[erow] * 320;
        size_t rbase = (size_t)sER[erow] * 320 + 160;
        lv[r] = *(const uint4*)&P[lbase + lx * 8];          // Lp perm cols {nt*16+lx}
        rv[r] = *(const uint4*)&P[rbase + lx * 8];          // Rp
        gl[r] = *(const u32*)&P[lbase + 128 + lx * 2];      // GLX: cols lx, 16+lx
        gr[r] = *(const u32*)&P[rbase + 128 + lx * 2];      // GR
    }

    f32x4 acc[8], accg[2];
#pragma unroll
    for (int i = 0; i < 8; ++i) { f32x4 z; z[0]=0;z[1]=0;z[2]=0;z[3]=0; acc[i] = z; }
    { f32x4 z; z[0]=0;z[1]=0;z[2]=0;z[3]=0; accg[0] = z; accg[1] = z; }

    // ---- GEMM1 (bond) + fused gate: no barriers, weights LDS-resident ----
#pragma unroll
    for (int ks = 0; ks < 4; ++ks) {
        bf16x8 af = *(const bf16x8*)&sA[(w * 16 + lx) * SA_LD + ks * 32 + quad * 8];
#pragma unroll
        for (int nt = 0; nt < 8; ++nt) {
            bf16x8 bf = *(const bf16x8*)&sW[((nt * 4 + ks) << 9) + lane * 8];
            acc[nt] = __builtin_amdgcn_mfma_f32_16x16x32_bf16(af, bf, acc[nt], 0, 0, 0);
        }
#pragma unroll
        for (int nt = 0; nt < 2; ++nt) {
            bf16x8 bf = *(const bf16x8*)&sW[16384 + ((nt * 4 + ks) << 9) + lane * 8];
            accg[nt] = __builtin_amdgcn_mfma_f32_16x16x32_bf16(af, bf, accg[nt], 0, 0, 0);
        }
    }

    // ---- gate epilogue (uses pre-gathered gl/gr) ----
    {
        float gw2a = gw2[lx], gw2b = gw2[16 + lx];
        float gb2v = gb2[0];
#pragma unroll
        for (int r = 0; r < 4; ++r) {
            float g0 = bf2f(gl[r] & 0xffff) + bf2f(gr[r] & 0xffff);   // orig col lx
            float g1 = bf2f(gl[r] >> 16) + bf2f(gr[r] >> 16);         // orig col 16+lx
            float v = fmaxf(accg[0][r] + g0, 0.f) * gw2a
                    + fmaxf(accg[1][r] + g1, 0.f) * gw2b;
            v += __shfl_xor(v, 1); v += __shfl_xor(v, 2);
            v += __shfl_xor(v, 4); v += __shfl_xor(v, 8);
            if (lx == 0) sG[w * 16 + quad * 4 + r] = 1.f / (1.f + __expf(-(v + gb2v)));
        }
    }

    // ---- t-epilogue: t = acc + Lp[el] + Rp[er] -> sA (own-wave rows, no barrier) ----
#pragma unroll
    for (int r = 0; r < 4; ++r) {
        int erow = w * 16 + quad * 4 + r;
        const u32* lw_ = (const u32*)&lv[r];
        const u32* rw_ = (const u32*)&rv[r];
#pragma unroll
        for (int nt = 0; nt < 8; ++nt) {
            u32 lh = (nt & 1) ? (lw_[nt >> 1] >> 16) : (lw_[nt >> 1] & 0xffff);
            u32 rh = (nt & 1) ? (rw_[nt >> 1] >> 16) : (rw_[nt >> 1] & 0xffff);
            float tv = acc[nt][r] + bf2f(lh) + bf2f(rh);
            sA[erow * SA_LD + nt * 16 + lx] = f2bf(tv);
        }
    }
    // re-init acc with inter_b1 (per output column)
#pragma unroll
    for (int nt = 0; nt < 8; ++nt) {
        float b = ib1[nt * 16 + lx];
        f32x4 t; t[0] = b; t[1] = b; t[2] = b; t[3] = b; acc[nt] = t;
    }

    __syncthreads();                                        // B2: all GEMM1 sW reads done
    // restage inter_w1 over bond region (fragment order, linear copy)
#pragma unroll
    for (int j = 0; j < 4; ++j) {
        int t = j * 512 + tid;
        *(uint4*)&sW[t * 8] = *(const uint4*)&iw1w[t * 8];
    }
    __syncthreads();                                        // B3: iw1 staged

    // ---- GEMM2 (inter_w1): no barriers ----
#pragma unroll
    for (int ks = 0; ks < 4; ++ks) {
        bf16x8 af = *(const bf16x8*)&sA[(w * 16 + lx) * SA_LD + ks * 32 + quad * 8];
#pragma unroll
        for (int nt = 0; nt < 8; ++nt) {
            bf16x8 bf = *(const bf16x8*)&sW[((nt * 4 + ks) << 9) + lane * 8];
            acc[nt] = __builtin_amdgcn_mfma_f32_16x16x32_bf16(af, bf, acc[nt], 0, 0, 0);
        }
    }

    // ---- inter epilogue: relu, dot iw2, lane-reduce ----
    {
        float ib2v = ib2[0];
        float iw2v[8];
#pragma unroll
        for (int nt = 0; nt < 8; ++nt) iw2v[nt] = iw2[nt * 16 + lx];
#pragma unroll
        for (int r = 0; r < 4; ++r) {
            float v = 0.f;
#pragma unroll
            for (int nt = 0; nt < 8; ++nt)
                v += fmaxf(acc[nt][r], 0.f) * iw2v[nt];
            v += __shfl_xor(v, 1); v += __shfl_xor(v, 2);
            v += __shfl_xor(v, 4); v += __shfl_xor(v, 8);
            if (lx == 0) sIS[w * 16 + quad * 4 + r] = v + ib2v;
        }
    }
    __syncthreads();                                        // B4

    // ---- force + scatter: 4 threads/edge, 3 active (component-parallel) ----
    {
        int e = tid >> 2, c = tid & 3;
        if (c < 3) {
            float wgt = sIS[e] * sG[e];
            float d = dist[eb + e];
            float coef = 5.f * wgt / ((d + 1e-6f) * (d + 5.f));
            atomicAdd(&dp[sEL[e] * 3 + c], coef * rel_vec[(size_t)(eb + e) * 3 + c]);
        }
    }
}

// ---------------------------------------------------------------------------
// Build scale-MLP input Xc[50000][160] bf16 = [h_node(128), ne(2), nrm, zeros(29)]
// ---------------------------------------------------------------------------
__global__ void build_xc(u16* __restrict__ Xc, const float* __restrict__ h_node,
                         const float* __restrict__ ne, const float* __restrict__ dp)
{
    int idx = blockIdx.x * 256 + threadIdx.x;
    if (idx >= N_NODES * 160) return;
    int n = idx / 160, c = idx % 160;
    float v;
    if (c < 128) v = h_node[(size_t)n * 128 + c];
    else if (c == 128) v = ne[n * 2];
    else if (c == 129) v = ne[n * 2 + 1];
    else if (c == 130) {
        float x = dp[n * 3], y = dp[n * 3 + 1], z = dp[n * 3 + 2];
        v = sqrtf(x * x + y * y + z * z);
    } else v = 0.f;
    Xc[idx] = f2bf(v);
}

// ---------------------------------------------------------------------------
// out[n] = dp[n] * sigmoid(U[n] . scale_w2 + sb2)     (U bf16)
// ---------------------------------------------------------------------------
__global__ __launch_bounds__(256)
void finalize(const u16* __restrict__ U, const float* __restrict__ sw2,
              const float* __restrict__ sb2, const float* __restrict__ dp,
              float* __restrict__ out)
{
    int node = blockIdx.x * 4 + (threadIdx.x >> 6);
    int lane = threadIdx.x & 63;
    const u16* u = &U[(size_t)node * 128];
    float p = bf2f(u[lane]) * sw2[lane] + bf2f(u[lane + 64]) * sw2[lane + 64];
    p += __shfl_xor(p, 1);  p += __shfl_xor(p, 2);
    p += __shfl_xor(p, 4);  p += __shfl_xor(p, 8);
    p += __shfl_xor(p, 16); p += __shfl_xor(p, 32);
    if (lane == 0) {
        float s = 1.f / (1.f + __expf(-(p + sb2[0])));
        out[node * 3 + 0] = dp[node * 3 + 0] * s;
        out[node * 3 + 1] = dp[node * 3 + 1] * s;
        out[node * 3 + 2] = dp[node * 3 + 2] * s;
    }
}

extern "C" void kernel_launch(void* const* d_in, const int* in_sizes, int n_in,
                              void* d_out, int out_size, void* d_ws, size_t ws_size,
                              hipStream_t stream)
{
    const float* h_node  = (const float*)d_in[0];
    const float* h_edge  = (const float*)d_in[1];
    const int*   eidx    = (const int*)  d_in[2];
    const float* rel_vec = (const float*)d_in[3];
    const float* dist    = (const float*)d_in[4];
    const float* ne      = (const float*)d_in[5];
    const float* lw1 = (const float*)d_in[6];  const float* lb1 = (const float*)d_in[7];
    const float* lw2 = (const float*)d_in[8];  const float* lb2 = (const float*)d_in[9];
    const float* rw1 = (const float*)d_in[10]; const float* rb1 = (const float*)d_in[11];
    const float* rw2 = (const float*)d_in[12]; const float* rb2 = (const float*)d_in[13];
    const float* bond_w  = (const float*)d_in[14];
    const float* nodeb_w = (const float*)d_in[15];
    const float* iw1 = (const float*)d_in[16]; const float* ib1 = (const float*)d_in[17];
    const float* iw2 = (const float*)d_in[18]; const float* ib2 = (const float*)d_in[19];
    const float* gw1 = (const float*)d_in[20]; const float* gb1 = (const float*)d_in[21];
    const float* gw2 = (const float*)d_in[22]; const float* gb2 = (const float*)d_in[23];
    const float* sw1 = (const float*)d_in[24]; const float* sb1 = (const float*)d_in[25];
    const float* sw2 = (const float*)d_in[26]; const float* sb2 = (const float*)d_in[27];
    float* out = (float*)d_out;

    // ---- workspace carve (256B-aligned) ----
    char* base = (char*)d_ws;
    auto carve = [&](size_t bytes) { char* p = base; base += (bytes + 255) & ~(size_t)255; return p; };
    u16*  hnode_bf = (u16*) carve((size_t)N_NODES * 128 * 2);
    u16*  H1       = (u16*) carve((size_t)N_NODES * 256 * 2);
    u16*  P        = (u16*) carve((size_t)N_NODES * 320 * 2);
    u16*  Xc       = (u16*) carve((size_t)N_NODES * 160 * 2);
    u16*  U        = (u16*) carve((size_t)N_NODES * 128 * 2);
    u16*  W1cat    = (u16*) carve(256 * 128 * 2);
    u16*  WP       = (u16*) carve(320 * 256 * 2);
    u16*  bond_bf  = (u16*) carve(128 * 128 * 2);
    u16*  iw1_bf   = (u16*) carve(128 * 128 * 2);
    u16*  gate_bf  = (u16*) carve(32 * 128 * 2);
    u16*  sw1c     = (u16*) carve(128 * 160 * 2);
    float* b1cat   = (float*)carve(256 * 4);
    float* bP      = (float*)carve(320 * 4);
    float* dp      = (float*)carve((size_t)N_NODES * 3 * 4);

    hipMemsetAsync(dp, 0, (size_t)N_NODES * 3 * 4, stream);

    dim3 blk(256);
    conv_hnode<<<(N_NODES * 32 + 255) / 256, blk, 0, stream>>>(h_node, hnode_bf);
    prep_small<<<(90368 + 255) / 256, blk, 0, stream>>>(lw1, rw1, lb1, rb1, bond_w, iw1, gw1, sw1,
                                                        W1cat, b1cat, bond_bf, iw1_bf, gate_bf, sw1c);
    compose_wp<<<320, blk, 0, stream>>>(nodeb_w, gw1, lw2, rw2, lb2, rb2, gb1, WP, bP);

    const int MB = (N_NODES + 63) / 64;   // 782
    // H1 = relu(hnode @ [lw1;rw1]^T + [lb1;rb1])            [50000 x 256]
    mfma_gemm<true ><<<dim3(MB, 4), blk, 0, stream>>>(hnode_bf, 128, W1cat, 128, b1cat, H1, 256, N_NODES, 256, 128);
    // P = H1 @ WP^T + bP                                     [50000 x 320]  (Lp|GLX|Rp|GR, permuted)
    mfma_gemm<false><<<dim3(MB, 5), blk, 0, stream>>>(H1, 256, WP, 256, bP, P, 320, N_NODES, 320, 256);
    fix_glx<<<(N_NODES * 32 + 255) / 256, blk, 0, stream>>>(P, ne, gw1);

    edge_kernel<<<N_EDGES / 128, dim3(512), 0, stream>>>(h_edge, eidx, rel_vec, dist, P,
                                                         bond_bf, iw1_bf, gate_bf,
                                                         ib1, iw2, ib2, gw2, gb2, dp);

    build_xc<<<(N_NODES * 160 + 255) / 256, blk, 0, stream>>>(Xc, h_node, ne, dp);
    // U = relu(Xc @ sw1c^T + sb1)                            [50000 x 128]
    mfma_gemm<true ><<<dim3(MB, 2), blk, 0, stream>>>(Xc, 160, sw1c, 160, sb1, U, 128, N_NODES, 128, 160);
    finalize<<<N_NODES / 4, blk, 0, stream>>>(U, sw2, sb2, dp, out);
}

// Round 3
// 803.378 us; speedup vs baseline: 1.0450x; 1.0183x over previous
//
#include <hip/hip_runtime.h>
#include <math.h>

#define N_NODES 50000
#define N_EDGES 800000
#define NSLOT 8

using bf16x8 = __attribute__((ext_vector_type(8))) short;
using f32x4  = __attribute__((ext_vector_type(4))) float;
typedef unsigned short u16;
typedef unsigned int   u32;

__device__ __forceinline__ u16 f2bf(float f) {
    union { float f; u32 u; } v; v.f = f;
    u32 u = v.u + 0x7fffu + ((v.u >> 16) & 1u);   // round-to-nearest-even
    return (u16)(u >> 16);
}
__device__ __forceinline__ float bf2f(u32 h) {
    union { u32 u; float f; } v; v.u = h << 16;
    return v.f;
}

#define SA_LD 136   // edge A tile leading dim (bf16), 16B-aligned rows
#define SW_LD 40    // weight-panel leading dim (mfma_gemm only)
#define SC_LD 168   // scale_kernel leading dim (2-way bank alias only)

// ---------------------------------------------------------------------------
// Generic bf16 MFMA GEMM: C[MxN](bf16) = act(A[MxK] @ W[NxK]^T + bias)
// A is bf16 (AF32=false) or fp32 converted during staging (AF32=true).
// 64x64 tile, 256 threads (4 waves, wave w owns m-subtile w), K-step 32.
// ---------------------------------------------------------------------------
template<bool RELU, bool AF32>
__global__ __launch_bounds__(256, 4)
void mfma_gemm(const void* __restrict__ Av, int lda,
               const u16* __restrict__ W, int ldw,
               const float* __restrict__ bias,
               u16* __restrict__ C, int ldc,
               int M, int N, int K)
{
    __shared__ u16 sA[64 * SW_LD];
    __shared__ u16 sW[64 * SW_LD];
    const int tid = threadIdx.x;
    const int w = tid >> 6, lane = tid & 63, lx = lane & 15, quad = lane >> 4;
    const int m0 = blockIdx.x * 64, n0 = blockIdx.y * 64;
    const u16*   A16 = (const u16*)Av;
    const float* A32 = (const float*)Av;

    f32x4 acc[4];
#pragma unroll
    for (int nt = 0; nt < 4; ++nt) {
        float b = bias ? bias[n0 + nt * 16 + lx] : 0.f;
        f32x4 t; t[0] = b; t[1] = b; t[2] = b; t[3] = b; acc[nt] = t;
    }

    const int sr = tid >> 2;            // 0..63 panel row
    const int sseg = (tid & 3) * 8;     // k-offset within panel
    const int ksteps = K >> 5;
    for (int ks = 0; ks < ksteps; ++ks) {
        const int k0 = ks * 32;
        __syncthreads();
        int am = m0 + sr; if (am >= M) am = M - 1;
        if (AF32) {
            float4 u0 = *(const float4*)&A32[(size_t)am * lda + k0 + sseg];
            float4 u1 = *(const float4*)&A32[(size_t)am * lda + k0 + sseg + 4];
            uint4 o;
            o.x = (u32)f2bf(u0.x) | ((u32)f2bf(u0.y) << 16);
            o.y = (u32)f2bf(u0.z) | ((u32)f2bf(u0.w) << 16);
            o.z = (u32)f2bf(u1.x) | ((u32)f2bf(u1.y) << 16);
            o.w = (u32)f2bf(u1.z) | ((u32)f2bf(u1.w) << 16);
            *(uint4*)&sA[sr * SW_LD + sseg] = o;
        } else {
            uint4 va = *(const uint4*)&A16[(size_t)am * lda + k0 + sseg];
            *(uint4*)&sA[sr * SW_LD + sseg] = va;
        }
        uint4 vw = *(const uint4*)&W[(size_t)(n0 + sr) * ldw + k0 + sseg];
        *(uint4*)&sW[sr * SW_LD + sseg] = vw;
        __syncthreads();
        bf16x8 af = *(const bf16x8*)&sA[(w * 16 + lx) * SW_LD + quad * 8];
#pragma unroll
        for (int nt = 0; nt < 4; ++nt) {
            bf16x8 bf = *(const bf16x8*)&sW[(nt * 16 + lx) * SW_LD + quad * 8];
            acc[nt] = __builtin_amdgcn_mfma_f32_16x16x32_bf16(af, bf, acc[nt], 0, 0, 0);
        }
    }
#pragma unroll
    for (int r = 0; r < 4; ++r) {
        int m = m0 + w * 16 + quad * 4 + r;
        if (m >= M) continue;
#pragma unroll
        for (int nt = 0; nt < 4; ++nt) {
            float v = acc[nt][r];
            if (RELU) v = fmaxf(v, 0.f);
            C[(size_t)m * ldc + n0 + nt * 16 + lx] = f2bf(v);
        }
    }
}

// ---------------------------------------------------------------------------
// Small weight conversions, flat-indexed.
// bond_bf / iw1_bf / gate_bf in MFMA FRAGMENT order:
//   flat t = (((g*4 + ks)*4 + quad)*16 + lx)*8 + e
//   n = g*16 + lx (output row), k = ks*32 + quad*8 + e
// ce[2g..2g+1] = gw1[g][384..385] (node_extra gate coefficients).
// ---------------------------------------------------------------------------
__global__ void prep_small(const float* lw1, const float* rw1,
                           const float* lb1, const float* rb1,
                           const float* bond_w, const float* iw1, const float* gw1,
                           const float* sw1,
                           u16* W1cat, float* b1cat, u16* bond_bf, u16* iw1_bf,
                           u16* gate_bf, u16* sw1c, float* ce)
{
    int idx = blockIdx.x * 256 + threadIdx.x;
    if (idx < 32768) {
        int i = idx >> 7, k = idx & 127;
        float v = (i < 128) ? lw1[i * 128 + k] : rw1[(i - 128) * 128 + k];
        W1cat[idx] = f2bf(v);
    } else if (idx < 33024) {
        int i = idx - 32768;
        b1cat[i] = (i < 128) ? lb1[i] : rb1[i - 128];
    } else if (idx < 49408) {
        int t = idx - 33024;               // bond, frag order
        int e = t & 7, lx = (t >> 3) & 15, quad = (t >> 7) & 3;
        int ks = (t >> 9) & 3, g = t >> 11;
        int n = g * 16 + lx, k = ks * 32 + quad * 8 + e;
        bond_bf[t] = f2bf(bond_w[n * 128 + k]);
    } else if (idx < 65792) {
        int t = idx - 49408;               // inter_w1, frag order
        int e = t & 7, lx = (t >> 3) & 15, quad = (t >> 7) & 3;
        int ks = (t >> 9) & 3, g = t >> 11;
        int n = g * 16 + lx, k = ks * 32 + quad * 8 + e;
        iw1_bf[t] = f2bf(iw1[n * 128 + k]);
    } else if (idx < 69888) {
        int t = idx - 65792;               // gate (h_edge slice), frag order
        int e = t & 7, lx = (t >> 3) & 15, quad = (t >> 7) & 3;
        int ks = (t >> 9) & 3, g = t >> 11;
        int n = g * 16 + lx, k = ks * 32 + quad * 8 + e;
        gate_bf[t] = f2bf(gw1[(size_t)n * 386 + k]);
    } else if (idx < 90368) {
        int t = idx - 69888;
        int o = t / 160, k = t % 160;
        sw1c[t] = (k < 131) ? f2bf(sw1[(size_t)o * 131 + k]) : (u16)0;
    } else if (idx < 90432) {
        int t = idx - 90368;               // 64 floats: ce[2g+c] = gw1[g][384+c]
        int g = t >> 1, c = t & 1;
        ce[t] = gw1[(size_t)g * 386 + 384 + c];
    }
}

// ---------------------------------------------------------------------------
// Compose projection weights (fold lw2/rw2 into nodeb_lin_w & gate_w1 node slices)
// WP[320][256] bf16, rows PERMUTED for vectorized edge-kernel gathers.
// bP[320] = composed bias (incl gb1 + w2-path bias for gate rows).
// ---------------------------------------------------------------------------
__global__ void compose_wp(const float* __restrict__ nodeb_w, const float* __restrict__ gw1,
                           const float* __restrict__ lw2, const float* __restrict__ rw2,
                           const float* __restrict__ lb2, const float* __restrict__ rb2,
                           const float* __restrict__ gb1,
                           u16* __restrict__ WP, float* __restrict__ bP)
{
    int idx = blockIdx.x * 256 + threadIdx.x;
    if (idx >= 320 * 256) return;
    int i = idx >> 8;      // permuted output row 0..319
    int j = idx & 255;     // K index 0..255
    bool leftRow = (i < 160);
    bool leftK = (j < 128);
    if (leftRow != leftK) { WP[idx] = 0; return; }

    const float* src;
    const float* w2 = leftRow ? lw2 : rw2;
    const float* b2 = leftRow ? lb2 : rb2;
    float biasExtra = 0.f;
    if (i < 128) {
        int c = ((i & 7) << 4) + (i >> 3);
        src = nodeb_w + (size_t)c * 256;
    } else if (i < 160) {
        int r = i - 128, g = ((r & 1) << 4) + (r >> 1);
        src = gw1 + (size_t)g * 386 + 128;
        biasExtra = gb1[g];
    } else if (i < 288) {
        int r = i - 160, c = ((r & 7) << 4) + (r >> 3);
        src = nodeb_w + (size_t)c * 256 + 128;
    } else {
        int r = i - 288, g = ((r & 1) << 4) + (r >> 1);
        src = gw1 + (size_t)g * 386 + 256;
    }
    int jj = j & 127;
    float s = 0.f;
#pragma unroll 4
    for (int k = 0; k < 128; ++k)
        s += src[k] * w2[(size_t)k * 128 + jj];
    WP[idx] = f2bf(s);
    if (jj == 0) {
        float b = biasExtra;
        for (int k = 0; k < 128; ++k) b += src[k] * b2[k];
        bP[i] = b;
    }
}

// ---------------------------------------------------------------------------
// Fused edge kernel: 128 edges/block, 512 threads (8 waves x 16 edges).
// node_extra gate term fused (ce table); dp privatized into NSLOT slots by
// blockIdx&7 to cut same-address atomic serialization 8x.
// ---------------------------------------------------------------------------
__global__ __launch_bounds__(512, 4)
void edge_kernel(const float* __restrict__ he,
                 const int*   __restrict__ eidx,
                 const float* __restrict__ rel_vec,
                 const float* __restrict__ dist,
                 const u16*   __restrict__ P,
                 const u16*   __restrict__ bondw,
                 const u16*   __restrict__ iw1w,
                 const u16*   __restrict__ gatew,
                 const float* __restrict__ ib1,
                 const float* __restrict__ iw2,
                 const float* __restrict__ ib2,
                 const float* __restrict__ gw2,
                 const float* __restrict__ gb2,
                 const float* __restrict__ ne,
                 const float* __restrict__ ce,
                 float* __restrict__ dp)
{
    __shared__ u16 sA[128 * SA_LD];        // 34816 B
    __shared__ u16 sW[16384 + 4096];       // bond(32KB)+gate(8KB); iw1 restaged over bond
    __shared__ int sEL[128], sER[128];
    __shared__ float sG[128], sIS[128];

    const int tid = threadIdx.x;
    const int w = tid >> 6, lane = tid & 63, lx = lane & 15, quad = lane >> 4;
    const int eb = blockIdx.x * 128;

    if (tid < 128) { sEL[tid] = eidx[eb + tid]; sER[tid] = eidx[N_EDGES + eb + tid]; }

    // stage GEMM1 weights (fragment-order = linear copy)
#pragma unroll
    for (int j = 0; j < 4; ++j) {
        int t = j * 512 + tid;
        *(uint4*)&sW[t * 8] = *(const uint4*)&bondw[t * 8];
    }
    *(uint4*)&sW[16384 + tid * 8] = *(const uint4*)&gatew[tid * 8];

    // stage h_edge tile -> bf16 LDS
#pragma unroll
    for (int j = 0; j < 8; ++j) {
        int fid = j * 512 + tid;
        int e = fid >> 5, kq = (fid & 31) << 2;
        float4 v = *(const float4*)&he[(size_t)(eb + e) * 128 + kq];
        uint2 o;
        o.x = (u32)f2bf(v.x) | ((u32)f2bf(v.y) << 16);
        o.y = (u32)f2bf(v.z) | ((u32)f2bf(v.w) << 16);
        *(uint2*)&sA[e * SA_LD + kq] = o;
    }
    __syncthreads();                                        // B1

    // ---- P gathers; Lp+Rp pre-summed into packed bf16 (register relief) ----
    uint4 lsum[4]; u32 gl[4], gr[4];
#pragma unroll
    for (int r = 0; r < 4; ++r) {
        int erow = w * 16 + quad * 4 + r;
        size_t lbase = (size_t)sEL[erow] * 320;
        size_t rbase = (size_t)sER[erow] * 320 + 160;
        uint4 lv = *(const uint4*)&P[lbase + lx * 8];
        uint4 rv = *(const uint4*)&P[rbase + lx * 8];
        gl[r] = *(const u32*)&P[lbase + 128 + lx * 2];
        gr[r] = *(const u32*)&P[rbase + 128 + lx * 2];
        const u32* lw_ = (const u32*)&lv;
        const u32* rw_ = (const u32*)&rv;
        uint4 o; u32* op = (u32*)&o;
#pragma unroll
        for (int q = 0; q < 4; ++q) {
            float lo = bf2f(lw_[q] & 0xffff) + bf2f(rw_[q] & 0xffff);
            float hi = bf2f(lw_[q] >> 16) + bf2f(rw_[q] >> 16);
            op[q] = (u32)f2bf(lo) | ((u32)f2bf(hi) << 16);
        }
        lsum[r] = o;
    }

    f32x4 acc[8], accg[2];
#pragma unroll
    for (int i = 0; i < 8; ++i) { f32x4 z; z[0]=0;z[1]=0;z[2]=0;z[3]=0; acc[i] = z; }
    { f32x4 z; z[0]=0;z[1]=0;z[2]=0;z[3]=0; accg[0] = z; accg[1] = z; }

    // ---- GEMM1 (bond) + fused gate ----
#pragma unroll
    for (int ks = 0; ks < 4; ++ks) {
        bf16x8 af = *(const bf16x8*)&sA[(w * 16 + lx) * SA_LD + ks * 32 + quad * 8];
#pragma unroll
        for (int nt = 0; nt < 8; ++nt) {
            bf16x8 bf = *(const bf16x8*)&sW[((nt * 4 + ks) << 9) + lane * 8];
            acc[nt] = __builtin_amdgcn_mfma_f32_16x16x32_bf16(af, bf, acc[nt], 0, 0, 0);
        }
#pragma unroll
        for (int nt = 0; nt < 2; ++nt) {
            bf16x8 bf = *(const bf16x8*)&sW[16384 + ((nt * 4 + ks) << 9) + lane * 8];
            accg[nt] = __builtin_amdgcn_mfma_f32_16x16x32_bf16(af, bf, accg[nt], 0, 0, 0);
        }
    }

    // ---- gate epilogue (ne term fused in, replacing fix_glx) ----
    {
        const float2* ce2 = (const float2*)ce;
        float2 cA = ce2[lx], cB = ce2[16 + lx];
        float gw2a = gw2[lx], gw2b = gw2[16 + lx];
        float gb2v = gb2[0];
#pragma unroll
        for (int r = 0; r < 4; ++r) {
            int erow = w * 16 + quad * 4 + r;
            float2 nv = *(const float2*)&ne[(size_t)sEL[erow] * 2];
            float g0 = bf2f(gl[r] & 0xffff) + bf2f(gr[r] & 0xffff)
                     + nv.x * cA.x + nv.y * cA.y;
            float g1 = bf2f(gl[r] >> 16) + bf2f(gr[r] >> 16)
                     + nv.x * cB.x + nv.y * cB.y;
            float v = fmaxf(accg[0][r] + g0, 0.f) * gw2a
                    + fmaxf(accg[1][r] + g1, 0.f) * gw2b;
            v += __shfl_xor(v, 1); v += __shfl_xor(v, 2);
            v += __shfl_xor(v, 4); v += __shfl_xor(v, 8);
            if (lx == 0) sG[erow] = 1.f / (1.f + __expf(-(v + gb2v)));
        }
    }

    // ---- t-epilogue: t = acc + (Lp+Rp) -> sA (own-wave rows, no barrier) ----
#pragma unroll
    for (int r = 0; r < 4; ++r) {
        int erow = w * 16 + quad * 4 + r;
        const u32* sw_ = (const u32*)&lsum[r];
#pragma unroll
        for (int nt = 0; nt < 8; ++nt) {
            u32 h = (nt & 1) ? (sw_[nt >> 1] >> 16) : (sw_[nt >> 1] & 0xffff);
            float tv = acc[nt][r] + bf2f(h);
            sA[erow * SA_LD + nt * 16 + lx] = f2bf(tv);
        }
    }
#pragma unroll
    for (int nt = 0; nt < 8; ++nt) {
        float b = ib1[nt * 16 + lx];
        f32x4 t; t[0] = b; t[1] = b; t[2] = b; t[3] = b; acc[nt] = t;
    }

    __syncthreads();                                        // B2
#pragma unroll
    for (int j = 0; j < 4; ++j) {
        int t = j * 512 + tid;
        *(uint4*)&sW[t * 8] = *(const uint4*)&iw1w[t * 8];
    }
    __syncthreads();                                        // B3

    // ---- GEMM2 (inter_w1) ----
#pragma unroll
    for (int ks = 0; ks < 4; ++ks) {
        bf16x8 af = *(const bf16x8*)&sA[(w * 16 + lx) * SA_LD + ks * 32 + quad * 8];
#pragma unroll
        for (int nt = 0; nt < 8; ++nt) {
            bf16x8 bf = *(const bf16x8*)&sW[((nt * 4 + ks) << 9) + lane * 8];
            acc[nt] = __builtin_amdgcn_mfma_f32_16x16x32_bf16(af, bf, acc[nt], 0, 0, 0);
        }
    }

    // ---- inter epilogue ----
    {
        float ib2v = ib2[0];
        float iw2v[8];
#pragma unroll
        for (int nt = 0; nt < 8; ++nt) iw2v[nt] = iw2[nt * 16 + lx];
#pragma unroll
        for (int r = 0; r < 4; ++r) {
            float v = 0.f;
#pragma unroll
            for (int nt = 0; nt < 8; ++nt)
                v += fmaxf(acc[nt][r], 0.f) * iw2v[nt];
            v += __shfl_xor(v, 1); v += __shfl_xor(v, 2);
            v += __shfl_xor(v, 4); v += __shfl_xor(v, 8);
            if (lx == 0) sIS[w * 16 + quad * 4 + r] = v + ib2v;
        }
    }
    __syncthreads();                                        // B4

    // ---- force + scatter into private slot ----
    {
        float* dps = dp + (size_t)(blockIdx.x & (NSLOT - 1)) * (3 * N_NODES);
        int e = tid >> 2, c = tid & 3;
        if (c < 3) {
            float wgt = sIS[e] * sG[e];
            float d = dist[eb + e];
            float coef = 5.f * wgt / ((d + 1e-6f) * (d + 5.f));
            atomicAdd(&dps[sEL[e] * 3 + c], coef * rel_vec[(size_t)(eb + e) * 3 + c]);
        }
    }
}

// ---------------------------------------------------------------------------
// Fused scale pipeline (replaces build_xc + U-GEMM + finalize):
// per 64-node block: A = [h_node | ne | nrm(Σslots dp) | 0] bf16 on the fly,
// U = relu(A @ sw1c^T + sb1) in-register, out = dp * sigmoid(U.sw2 + sb2).
// ---------------------------------------------------------------------------
__global__ __launch_bounds__(256, 4)
void scale_kernel(const float* __restrict__ h_node,
                  const float* __restrict__ ne,
                  const float* __restrict__ dp,      // NSLOT slots
                  const u16*   __restrict__ sw1c,    // [128][160] bf16 (zero-padded)
                  const float* __restrict__ sb1,
                  const float* __restrict__ sw2,
                  const float* __restrict__ sb2,
                  float* __restrict__ out)
{
    __shared__ u16 sA[64 * SC_LD];
    __shared__ u16 sW[128 * SC_LD];
    __shared__ float sDP[64][3];
    const int tid = threadIdx.x;
    const int w = tid >> 6, lane = tid & 63, lx = lane & 15, quad = lane >> 4;
    const int m0 = blockIdx.x * 64;

    // A cols 0..127 from h_node fp32
#pragma unroll
    for (int j = 0; j < 4; ++j) {
        int id = j * 256 + tid;
        int r = id >> 4, c8 = (id & 15) << 3;
        int am = m0 + r; if (am >= N_NODES) am = N_NODES - 1;
        float4 u0 = *(const float4*)&h_node[(size_t)am * 128 + c8];
        float4 u1 = *(const float4*)&h_node[(size_t)am * 128 + c8 + 4];
        uint4 o;
        o.x = (u32)f2bf(u0.x) | ((u32)f2bf(u0.y) << 16);
        o.y = (u32)f2bf(u0.z) | ((u32)f2bf(u0.w) << 16);
        o.z = (u32)f2bf(u1.x) | ((u32)f2bf(u1.y) << 16);
        o.w = (u32)f2bf(u1.z) | ((u32)f2bf(u1.w) << 16);
        *(uint4*)&sA[r * SC_LD + c8] = o;
    }
    // W from sw1c [128][160]
#pragma unroll
    for (int j = 0; j < 10; ++j) {
        int id = j * 256 + tid;
        int r = id / 20, c8 = (id % 20) * 8;
        *(uint4*)&sW[r * SC_LD + c8] = *(const uint4*)&sw1c[r * 160 + c8];
    }
    // special cols 128..159 + dp slot-sums
    if (tid < 64) {
        int am = m0 + tid; if (am >= N_NODES) am = N_NODES - 1;
        float sx = 0.f, sy = 0.f, sz = 0.f;
#pragma unroll
        for (int s = 0; s < NSLOT; ++s) {
            const float* d = dp + (size_t)s * (3 * N_NODES) + (size_t)am * 3;
            sx += d[0]; sy += d[1]; sz += d[2];
        }
        sDP[tid][0] = sx; sDP[tid][1] = sy; sDP[tid][2] = sz;
        float2 nv = *(const float2*)&ne[(size_t)am * 2];
        u16* row = &sA[tid * SC_LD];
        row[128] = f2bf(nv.x); row[129] = f2bf(nv.y);
        row[130] = f2bf(sqrtf(sx * sx + sy * sy + sz * sz));
#pragma unroll
        for (int c = 131; c < 160; ++c) row[c] = 0;
    }

    f32x4 acc[8];
#pragma unroll
    for (int nt = 0; nt < 8; ++nt) {
        float b = sb1[nt * 16 + lx];
        f32x4 t; t[0] = b; t[1] = b; t[2] = b; t[3] = b; acc[nt] = t;
    }
    __syncthreads();

#pragma unroll
    for (int ks = 0; ks < 5; ++ks) {
        bf16x8 af = *(const bf16x8*)&sA[(w * 16 + lx) * SC_LD + ks * 32 + quad * 8];
#pragma unroll
        for (int nt = 0; nt < 8; ++nt) {
            bf16x8 bf = *(const bf16x8*)&sW[(nt * 16 + lx) * SC_LD + ks * 32 + quad * 8];
            acc[nt] = __builtin_amdgcn_mfma_f32_16x16x32_bf16(af, bf, acc[nt], 0, 0, 0);
        }
    }

    float sw2v[8];
#pragma unroll
    for (int nt = 0; nt < 8; ++nt) sw2v[nt] = sw2[nt * 16 + lx];
    float sb2v = sb2[0];
#pragma unroll
    for (int r = 0; r < 4; ++r) {
        int m = m0 + w * 16 + quad * 4 + r;
        float v = 0.f;
#pragma unroll
        for (int nt = 0; nt < 8; ++nt) v += fmaxf(acc[nt][r], 0.f) * sw2v[nt];
        v += __shfl_xor(v, 1); v += __shfl_xor(v, 2);
        v += __shfl_xor(v, 4); v += __shfl_xor(v, 8);
        if (lx == 0 && m < N_NODES) {
            float s = 1.f / (1.f + __expf(-(v + sb2v)));
            int lr = w * 16 + quad * 4 + r;
            out[m * 3 + 0] = sDP[lr][0] * s;
            out[m * 3 + 1] = sDP[lr][1] * s;
            out[m * 3 + 2] = sDP[lr][2] * s;
        }
    }
}

extern "C" void kernel_launch(void* const* d_in, const int* in_sizes, int n_in,
                              void* d_out, int out_size, void* d_ws, size_t ws_size,
                              hipStream_t stream)
{
    const float* h_node  = (const float*)d_in[0];
    const float* h_edge  = (const float*)d_in[1];
    const int*   eidx    = (const int*)  d_in[2];
    const float* rel_vec = (const float*)d_in[3];
    const float* dist    = (const float*)d_in[4];
    const float* ne      = (const float*)d_in[5];
    const float* lw1 = (const float*)d_in[6];  const float* lb1 = (const float*)d_in[7];
    const float* lw2 = (const float*)d_in[8];  const float* lb2 = (const float*)d_in[9];
    const float* rw1 = (const float*)d_in[10]; const float* rb1 = (const float*)d_in[11];
    const float* rw2 = (const float*)d_in[12]; const float* rb2 = (const float*)d_in[13];
    const float* bond_w  = (const float*)d_in[14];
    const float* nodeb_w = (const float*)d_in[15];
    const float* iw1 = (const float*)d_in[16]; const float* ib1 = (const float*)d_in[17];
    const float* iw2 = (const float*)d_in[18]; const float* ib2 = (const float*)d_in[19];
    const float* gw1 = (const float*)d_in[20]; const float* gb1 = (const float*)d_in[21];
    const float* gw2 = (const float*)d_in[22]; const float* gb2 = (const float*)d_in[23];
    const float* sw1 = (const float*)d_in[24]; const float* sb1 = (const float*)d_in[25];
    const float* sw2 = (const float*)d_in[26]; const float* sb2 = (const float*)d_in[27];
    float* out = (float*)d_out;

    // ---- workspace carve (256B-aligned) ----
    char* base = (char*)d_ws;
    auto carve = [&](size_t bytes) { char* p = base; base += (bytes + 255) & ~(size_t)255; return p; };
    u16*  H1      = (u16*) carve((size_t)N_NODES * 256 * 2);
    u16*  P       = (u16*) carve((size_t)N_NODES * 320 * 2);
    u16*  W1cat   = (u16*) carve(256 * 128 * 2);
    u16*  WP      = (u16*) carve(320 * 256 * 2);
    u16*  bond_bf = (u16*) carve(128 * 128 * 2);
    u16*  iw1_bf  = (u16*) carve(128 * 128 * 2);
    u16*  gate_bf = (u16*) carve(32 * 128 * 2);
    u16*  sw1c    = (u16*) carve(128 * 160 * 2);
    float* b1cat  = (float*)carve(256 * 4);
    float* bP     = (float*)carve(320 * 4);
    float* ce     = (float*)carve(64 * 4);
    float* dp     = (float*)carve((size_t)NSLOT * N_NODES * 3 * 4);

    hipMemsetAsync(dp, 0, (size_t)NSLOT * N_NODES * 3 * 4, stream);

    dim3 blk(256);
    prep_small<<<(90432 + 255) / 256, blk, 0, stream>>>(lw1, rw1, lb1, rb1, bond_w, iw1, gw1, sw1,
                                                        W1cat, b1cat, bond_bf, iw1_bf, gate_bf, sw1c, ce);
    compose_wp<<<320, blk, 0, stream>>>(nodeb_w, gw1, lw2, rw2, lb2, rb2, gb1, WP, bP);

    const int MB = (N_NODES + 63) / 64;   // 782
    // H1 = relu(h_node @ [lw1;rw1]^T + [lb1;rb1])   (fp32 A converted in staging)
    mfma_gemm<true, true ><<<dim3(MB, 4), blk, 0, stream>>>(h_node, 128, W1cat, 128, b1cat, H1, 256, N_NODES, 256, 128);
    // P = H1 @ WP^T + bP    [50000 x 320]  (Lp|GLX|Rp|GR, permuted)
    mfma_gemm<false, false><<<dim3(MB, 5), blk, 0, stream>>>(H1, 256, WP, 256, bP, P, 320, N_NODES, 320, 256);

    edge_kernel<<<N_EDGES / 128, dim3(512), 0, stream>>>(h_edge, eidx, rel_vec, dist, P,
                                                         bond_bf, iw1_bf, gate_bf,
                                                         ib1, iw2, ib2, gw2, gb2, ne, ce, dp);

    scale_kernel<<<MB, blk, 0, stream>>>(h_node, ne, dp, sw1c, sb1, sw2, sb2, out);
}